// Round 20
// baseline (2049.952 us; speedup 1.0000x reference)
//
#include <hip/hip_runtime.h>
#include <hip/hip_bf16.h>
#include <math.h>

#define D_      512
#define NPATCH  56
#define DFF_    2048
#define NLAYER  6
#define HEADS   8
#define DH_     64
#define HOR_    24
#define BATCH_  512
#define NTOK_   (BATCH_ * NPATCH)
#define KPAD    96                  // patch K=72 padded to 96 (mult of 32)

typedef __hip_bfloat16 bf16;
typedef __bf16 bf16x8 __attribute__((ext_vector_type(8)));
typedef float  f32x4  __attribute__((ext_vector_type(4)));

__device__ __forceinline__ void gload_lds16(const void* g, void* lds) {
    __builtin_amdgcn_global_load_lds(
        (const __attribute__((address_space(1))) unsigned int*)g,
        (__attribute__((address_space(3))) unsigned int*)lds, 16, 0, 0);
}

// ---------------- block-wide sum over 256 threads ----------------
__device__ __forceinline__ float block_sum256(float v) {
    __shared__ float sm[4];
    const int lane = threadIdx.x & 63;
    const int w    = threadIdx.x >> 6;
    #pragma unroll
    for (int o = 32; o > 0; o >>= 1) v += __shfl_down(v, o);
    __syncthreads();
    if (lane == 0) sm[w] = v;
    __syncthreads();
    return sm[0] + sm[1] + sm[2] + sm[3];
}

// fast tanh-GELU: 0.5x(1+tanh(.79788(x+.044715x^3))) = x - x*rcp(1+exp(2u))
__device__ __forceinline__ float gelu_fast(float xg) {
    const float e = __expf(1.5957691216057308f * (xg + 0.044715f * xg * xg * xg));
    return xg - xg * __builtin_amdgcn_rcpf(1.f + e);
}

// ---- pack f32 weight W[Keff][N] (row-major, output col = n) into bf16 MFMA
// B-fragment stream: out[(((bandoff+c64)*nt + t)*4 + n)*64 + l] (bf16x8 units)
//   = W[(t*32+(l>>4)*8+e)][c64*64 + n*16 + (l&15)], zero-padded for k >= Keff.
__global__ __launch_bounds__(256) void packW_k(
    const float* __restrict__ W, bf16* __restrict__ out,
    int N, int K, int Keff, int bandoff, size_t w_ls, size_t o_ls)
{
    W   += (size_t)blockIdx.z * w_ls;
    out += (size_t)blockIdx.z * o_ls;
    const int idx = blockIdx.x * 256 + threadIdx.x;
    if (idx >= (N * K) >> 3) return;
    const int nt  = K >> 5;
    const int l   = idx & 63;
    const int n   = (idx >> 6) & 3;
    const int t   = (idx >> 8) % nt;
    const int c64 = (idx >> 8) / nt;
    const int row = c64 * 64 + n * 16 + (l & 15);
    const int kk  = t * 32 + (l >> 4) * 8;
    bf16x8 v;
    #pragma unroll
    for (int e = 0; e < 8; e++)
        v[e] = (kk + e < Keff) ? (__bf16)W[(size_t)(kk + e) * N + row] : (__bf16)0.f;
    const size_t oidx = ((((size_t)(bandoff + c64) * nt + t) * 4 + n) * 64 + l) * 8;
    *(bf16x8*)((__bf16*)out + oidx) = v;
}

// ---------------- x [NTOK][72] f32 -> [NTOK][96] bf16 zero-padded ----------------
__global__ __launch_bounds__(256) void xpad_k(
    const float* __restrict__ x, bf16* __restrict__ out)
{
    const size_t idx = (size_t)blockIdx.x * 256 + threadIdx.x;
    if (idx >= (size_t)NTOK_ * KPAD) return;
    const size_t row = idx / KPAD;
    const int kk = (int)(idx - row * KPAD);
    out[idx] = (kk < 72) ? __float2bfloat16(x[row * 72 + kk]) : __float2bfloat16(0.f);
}

// ---------------- concat q/k/v biases -> [NL][1536] f32 ----------------
__global__ __launch_bounds__(256) void bqkv_k(
    const float* __restrict__ bq, const float* __restrict__ bk,
    const float* __restrict__ bv, float* __restrict__ o)
{
    const int idx = blockIdx.x * 256 + threadIdx.x;
    if (idx >= NLAYER * 3 * D_) return;
    const int l = idx / (3 * D_), n = idx % (3 * D_);
    float v;
    if      (n < D_)     v = bq[l * D_ + n];
    else if (n < 2 * D_) v = bk[l * D_ + n - D_];
    else                 v = bv[l * D_ + n - 2 * D_];
    o[idx] = v;
}

// ---------------- LayerNorm: bf16 in -> bf16 out, one wave per row (8 rows/block) ----
__global__ __launch_bounds__(512) void layernorm_bf16_k(
    const bf16* __restrict__ x, const float* __restrict__ g,
    const float* __restrict__ b, bf16* __restrict__ y)
{
    const int w = threadIdx.x >> 6, lane = threadIdx.x & 63;
    const size_t row = (size_t)blockIdx.x * 8 + w;
    const bf16x8 a8 = *(const bf16x8*)((const __bf16*)x + row * D_ + lane * 8);
    float a[8];
    #pragma unroll
    for (int i = 0; i < 8; i++) a[i] = (float)a8[i];
    float s = 0.f;
    #pragma unroll
    for (int i = 0; i < 8; i++) s += a[i];
    #pragma unroll
    for (int o = 32; o > 0; o >>= 1) s += __shfl_xor(s, o);
    const float mean = s * (1.f / 512.f);
    float d[8];
    #pragma unroll
    for (int i = 0; i < 8; i++) d[i] = a[i] - mean;
    float v = 0.f;
    #pragma unroll
    for (int i = 0; i < 8; i++) v += d[i] * d[i];
    #pragma unroll
    for (int o = 32; o > 0; o >>= 1) v += __shfl_xor(v, o);
    const float rstd = rsqrtf(v * (1.f / 512.f) + 1e-5f);
    const float4 g0 = *(const float4*)(g + lane * 8);
    const float4 g1 = *(const float4*)(g + lane * 8 + 4);
    const float4 b0 = *(const float4*)(b + lane * 8);
    const float4 b1 = *(const float4*)(b + lane * 8 + 4);
    const float gg[8] = {g0.x, g0.y, g0.z, g0.w, g1.x, g1.y, g1.z, g1.w};
    const float bb[8] = {b0.x, b0.y, b0.z, b0.w, b1.x, b1.y, b1.z, b1.w};
    bf16x8 o8;
    #pragma unroll
    for (int i = 0; i < 8; i++) o8[i] = (__bf16)(d[i] * rstd * gg[i] + bb[i]);
    *(bf16x8*)((__bf16*)y + row * D_ + lane * 8) = o8;
}

// ---------------- bf16 MFMA GEMM: C[M,N] = A[M,K] @ W^T via packed B fragments -------
// Tile 128M x 256N, 8 waves (2Mx4N), per-wave 64x64 (acc[4][4]). A: 3-ring LDS
// (24 KB), 1 gload_lds per wave per K-step, counted vmcnt(5) (age proof: >=8 VMEM
// ops issue after each A-stage before its wait, uniformly incl. tail iters).
// B: fragments pre-packed in stream order -> 4 coalesced 16B/lane register loads
// per K-step, prefetched one step ahead; compiler inserts exact waits for B regs.
// Coalesced quad-contiguous A staging; 16B chunk XOR-permuted within 64B line
// (same involution on stage source and frag read) -> conflict-free ds_read.
template<bool GELU, bool RESID, bool POS, bool QKVSPLIT>
__global__ __launch_bounds__(512, 2) void gemm_bf16_k(
    const bf16* __restrict__ A, const bf16* __restrict__ Bpk,
    const float* __restrict__ bias, const bf16* __restrict__ resid,
    const float* __restrict__ pos, bf16* __restrict__ Cp,
    bf16* __restrict__ vt, int M, int N, int K, int nx)
{
    __shared__ __align__(16) bf16 As[3][128 * 32];   // A only: 24 KB
    const int tid  = threadIdx.x;
    const int wid  = tid >> 6;        // 0..7
    const int lane = tid & 63;

    // bijective XCD swizzle (m204)
    const int nwg = gridDim.x;
    const int q8 = nwg >> 3, r8 = nwg & 7;
    const int xcd = blockIdx.x & 7, idx8 = blockIdx.x >> 3;
    const int swz = (xcd < r8 ? xcd * (q8 + 1) : r8 * (q8 + 1) + (xcd - r8) * q8) + idx8;
    const int n0 = (swz % nx) * 256;
    const int m0 = (swz / nx) * 128;
    const int wr = wid >> 2, wc = wid & 3;   // 2 row-bands x 4 col-bands of 64

    f32x4 acc[4][4];
    #pragma unroll
    for (int m = 0; m < 4; m++)
        #pragma unroll
        for (int n = 0; n < 4; n++) acc[m][n] = f32x4{0.f, 0.f, 0.f, 0.f};

    // A staging: wave wid stages segment wid (16 rows); quad covers one 64B line,
    // 16B chunk XOR-permuted within line.
    const int srow = lane >> 2;
    const int schunk = ((lane & 3) ^ ((lane >> 3) & 3)) * 8;
    const bf16* gA = A + (size_t)(m0 + wid * 16 + srow) * K + schunk;
    const int soff = wid * 512;

    // frag read: row fr, k-chunk qg stored at slot qg ^ ((fr>>1)&3)
    const int fr = lane & 15;
    const int qg = lane >> 4;
    const int roff = fr * 32 + ((qg ^ ((fr >> 1) & 3)) * 8);

    const int nt = K >> 5;
    // B fragment stream base for this wave's 64-col band (lane offset folded in)
    const bf16* gB = Bpk + (((size_t)((n0 >> 6) + wc) * nt * 4 + 0) * 64 + lane) * 8;
    // frag (t, n) at gB + t*2048 + n*512 elements

    #define STAGEA(buf, kt) gload_lds16(gA + ((kt) << 5), &As[buf][soff])

    // prologue: stage A steps 0,1; load B(0)
    STAGEA(0, 0);
    STAGEA(1, 1);
    bf16x8 bg[4], bgn[4];
    #pragma unroll
    for (int n = 0; n < 4; n++) bg[n] = *(const bf16x8*)(gB + (size_t)n * 512);

    int cur = 0, nxt = 2;
    for (int t = 0; t < nt; t++) {
        asm volatile("s_waitcnt vmcnt(5)" ::: "memory");   // A-stage(t) landed
        __builtin_amdgcn_s_barrier();
        __builtin_amdgcn_sched_barrier(0);
        bf16x8 af[4];
        #pragma unroll
        for (int m = 0; m < 4; m++)
            af[m] = *(const bf16x8*)&As[cur][(wr * 4 + m) * 512 + roff];
        if (t + 2 < nt) STAGEA(nxt, t + 2);
        if (t + 1 < nt) {
            const bf16* bp = gB + (size_t)(t + 1) * 2048;
            #pragma unroll
            for (int n = 0; n < 4; n++) bgn[n] = *(const bf16x8*)(bp + (size_t)n * 512);
        }
        __builtin_amdgcn_s_setprio(1);
        #pragma unroll
        for (int m = 0; m < 4; m++)
            #pragma unroll
            for (int n = 0; n < 4; n++)
                acc[m][n] = __builtin_amdgcn_mfma_f32_16x16x32_bf16(af[m], bg[n], acc[m][n], 0, 0, 0);
        __builtin_amdgcn_s_setprio(0);
        #pragma unroll
        for (int n = 0; n < 4; n++) bg[n] = bgn[n];
        cur = (cur == 2) ? 0 : cur + 1;
        nxt = (nxt == 2) ? 0 : nxt + 1;
    }
    #undef STAGEA

    const int rq = qg * 4;
    #pragma unroll
    for (int m = 0; m < 4; m++) {
        #pragma unroll
        for (int n = 0; n < 4; n++) {
            const int col = n0 + wc * 64 + n * 16 + fr;
            const float bcol = bias[col];
            #pragma unroll
            for (int j = 0; j < 4; j++) {
                const int row = m0 + wr * 64 + m * 16 + rq + j;
                float c = acc[m][n][j] + bcol;
                if (GELU)  c = gelu_fast(c);
                if (RESID) c += __bfloat162float(resid[(size_t)row * N + col]);
                if (POS)   c += pos[(size_t)(row % NPATCH) * D_ + col];
                if (QKVSPLIT) {
                    if (col < 1024) {
                        Cp[(size_t)row * 1024 + col] = __float2bfloat16(c);
                    } else {
                        const int c2 = col - 1024, hh = c2 >> 6, dd = c2 & 63;
                        const int bb = row / NPATCH, pp = row - bb * NPATCH;
                        vt[(((size_t)bb * 8 + hh) * 64 + dd) * 64 + pp] = __float2bfloat16(c);
                    }
                } else {
                    Cp[(size_t)row * N + col] = __float2bfloat16(c);
                }
            }
        }
    }
}

// ---------------- MFMA attention: 1 wave per (b,h); no cross-wave sync ----------------
__global__ __launch_bounds__(256) void attn_mfma_k(
    const bf16* __restrict__ qk, const bf16* __restrict__ vt,
    bf16* __restrict__ ao)
{
    __shared__ __align__(16) bf16 St[4][64 * 72];
    const int tid  = threadIdx.x;
    const int w    = tid >> 6, lane = tid & 63;
    const int bh   = blockIdx.x * 4 + w;
    const int b    = bh >> 3, hh = bh & 7;
    const int fr   = lane & 15;
    const int qg   = lane >> 4;
    const int kc   = qg * 8;

    const bf16* Qb = qk + (size_t)b * NPATCH * 1024 + hh * 64;
    const bf16* Kb = Qb + 512;
    const bf16* Vb = vt + (size_t)bh * 4096;

    bf16x8 qf[4][2], kf[4][2];
    #pragma unroll
    for (int m = 0; m < 4; m++)
        #pragma unroll
        for (int ks = 0; ks < 2; ks++) {
            qf[m][ks] = *(const bf16x8*)&Qb[(size_t)(m * 16 + fr) * 1024 + ks * 32 + kc];
            kf[m][ks] = *(const bf16x8*)&Kb[(size_t)(m * 16 + fr) * 1024 + ks * 32 + kc];
        }

    f32x4 acc[4][4];
    #pragma unroll
    for (int m = 0; m < 4; m++)
        #pragma unroll
        for (int n = 0; n < 4; n++) acc[m][n] = f32x4{0.f, 0.f, 0.f, 0.f};
    __builtin_amdgcn_s_setprio(1);
    #pragma unroll
    for (int ks = 0; ks < 2; ks++)
        #pragma unroll
        for (int m = 0; m < 4; m++)
            #pragma unroll
            for (int n = 0; n < 4; n++)
                acc[m][n] = __builtin_amdgcn_mfma_f32_16x16x32_bf16(qf[m][ks], kf[n][ks], acc[m][n], 0, 0, 0);
    __builtin_amdgcn_s_setprio(0);

    bf16x8 vf[4][2];
    #pragma unroll
    for (int n = 0; n < 4; n++)
        #pragma unroll
        for (int ks = 0; ks < 2; ks++)
            vf[n][ks] = *(const bf16x8*)&Vb[(size_t)(n * 16 + fr) * 64 + ks * 32 + kc];

    const float slope = exp2f(-(float)(hh + 1));
    bf16* Sw = St[w];
    #pragma unroll
    for (int m = 0; m < 4; m++) {
        #pragma unroll
        for (int j = 0; j < 4; j++) {
            const int r = m * 16 + qg * 4 + j;
            float s[4];
            #pragma unroll
            for (int n = 0; n < 4; n++) {
                const int col = n * 16 + fr;
                float sv = acc[m][n][j] * 0.125f - slope * fabsf((float)(r - col));
                s[n] = (col >= NPATCH) ? -1e30f : sv;
            }
            float mx = fmaxf(fmaxf(s[0], s[1]), fmaxf(s[2], s[3]));
            mx = fmaxf(mx, __shfl_xor(mx, 1));
            mx = fmaxf(mx, __shfl_xor(mx, 2));
            mx = fmaxf(mx, __shfl_xor(mx, 4));
            mx = fmaxf(mx, __shfl_xor(mx, 8));
            float p[4], sum = 0.f;
            #pragma unroll
            for (int n = 0; n < 4; n++) { p[n] = __expf(s[n] - mx); sum += p[n]; }
            sum += __shfl_xor(sum, 1);
            sum += __shfl_xor(sum, 2);
            sum += __shfl_xor(sum, 4);
            sum += __shfl_xor(sum, 8);
            const float inv = 1.f / sum;
            #pragma unroll
            for (int n = 0; n < 4; n++)
                Sw[r * 72 + n * 16 + fr] = __float2bfloat16(p[n] * inv);
        }
    }

    #pragma unroll
    for (int m = 0; m < 4; m++)
        #pragma unroll
        for (int n = 0; n < 4; n++) acc[m][n] = f32x4{0.f, 0.f, 0.f, 0.f};
    __builtin_amdgcn_s_setprio(1);
    #pragma unroll
    for (int m = 0; m < 4; m++)
        #pragma unroll
        for (int ks = 0; ks < 2; ks++) {
            const bf16x8 pf = *(const bf16x8*)&Sw[(m * 16 + fr) * 72 + ks * 32 + kc];
            #pragma unroll
            for (int n = 0; n < 4; n++)
                acc[m][n] = __builtin_amdgcn_mfma_f32_16x16x32_bf16(pf, vf[n][ks], acc[m][n], 0, 0, 0);
        }
    __builtin_amdgcn_s_setprio(0);

    bf16* Ob = ao + (size_t)b * NPATCH * 512 + hh * 64;
    #pragma unroll
    for (int m = 0; m < 4; m++)
        #pragma unroll
        for (int j = 0; j < 4; j++) {
            const int r = m * 16 + qg * 4 + j;
            if (r < NPATCH)
                #pragma unroll
                for (int n = 0; n < 4; n++)
                    Ob[(size_t)r * 512 + n * 16 + fr] = __float2bfloat16(acc[m][n][j]);
        }
}

// ---------------- fused mean pool + final LN + head (bf16 h): one block per row ------
__global__ __launch_bounds__(256) void head_k(
    const bf16* __restrict__ h, const float* __restrict__ g,
    const float* __restrict__ bb, const float* __restrict__ hW,
    const float* __restrict__ hb, float* __restrict__ out)
{
    const int b = blockIdx.x;
    __shared__ float row[D_];
    const int tid = threadIdx.x;
    float v0 = 0.f, v1 = 0.f;
    #pragma unroll
    for (int p = 0; p < NPATCH; p++) {
        const bf16* hr = h + (size_t)b * NPATCH * D_ + (size_t)p * D_;
        v0 += __bfloat162float(hr[tid]);
        v1 += __bfloat162float(hr[tid + 256]);
    }
    v0 *= (1.f / (float)NPATCH);
    v1 *= (1.f / (float)NPATCH);
    const float mean = block_sum256(v0 + v1) * (1.f / 512.f);
    const float d0 = v0 - mean, d1 = v1 - mean;
    const float var = block_sum256(d0 * d0 + d1 * d1) * (1.f / 512.f);
    const float rstd = rsqrtf(var + 1e-5f);
    row[tid]       = d0 * rstd * g[tid]       + bb[tid];
    row[tid + 256] = d1 * rstd * g[tid + 256] + bb[tid + 256];
    __syncthreads();
    if (tid < HOR_) {
        float acc = hb[tid];
        for (int kk = 0; kk < D_; kk++) acc = fmaf(row[kk], hW[kk * HOR_ + tid], acc);
        out[(size_t)b * HOR_ + tid] = acc;
    }
}

extern "C" void kernel_launch(void* const* d_in, const int* in_sizes, int n_in,
                              void* d_out, int out_size, void* d_ws, size_t ws_size,
                              hipStream_t stream)
{
    const float* x       = (const float*)d_in[0];
    const float* patch_W = (const float*)d_in[1];
    const float* patch_b = (const float*)d_in[2];
    const float* pos     = (const float*)d_in[3];
    const float* ln1_g   = (const float*)d_in[4];
    const float* ln1_b   = (const float*)d_in[5];
    const float* Wq      = (const float*)d_in[6];
    const float* bq      = (const float*)d_in[7];
    const float* Wk      = (const float*)d_in[8];
    const float* bk      = (const float*)d_in[9];
    const float* Wv      = (const float*)d_in[10];
    const float* bv      = (const float*)d_in[11];
    const float* Wo      = (const float*)d_in[12];
    const float* bo      = (const float*)d_in[13];
    const float* ln2_g   = (const float*)d_in[14];
    const float* ln2_b   = (const float*)d_in[15];
    const float* W1      = (const float*)d_in[16];
    const float* b1      = (const float*)d_in[17];
    const float* W2      = (const float*)d_in[18];
    const float* b2      = (const float*)d_in[19];
    const float* fn_g    = (const float*)d_in[20];
    const float* fn_b    = (const float*)d_in[21];
    const float* head_W  = (const float*)d_in[22];
    const float* head_b  = (const float*)d_in[23];
    float* out = (float*)d_out;

    // ---- workspace: packed weights (per-call), then activations ----
    const size_t WELEM  = (size_t)D_ * D_;
    const size_t WFELEM = (size_t)D_ * DFF_;
    bf16* wqkvp = (bf16*)d_ws;                        // [6][1536*512] packed frags
    bf16* wop   = wqkvp + (size_t)NLAYER * 3 * WELEM;
    bf16* w1p   = wop   + (size_t)NLAYER * WELEM;     // [6][2048*512]
    bf16* w2p   = w1p   + (size_t)NLAYER * WFELEM;    // [6][512*2048]
    bf16* pwp   = w2p   + (size_t)NLAYER * WFELEM;    // [512*96]
    float* bqkv = (float*)(pwp + (size_t)D_ * KPAD);  // [6][1536]
    bf16* xpad  = (bf16*)(bqkv + NLAYER * 3 * D_);    // [NTOK][96]
    char* wend  = (char*)(xpad + (size_t)NTOK_ * KPAD);
    const size_t FIXED = (size_t)(wend - (char*)d_ws);

    // per-token activation bytes: h 1024 + hn 1024 + qk 2048 + ao 1024 (all bf16)
    int BC = 16;
    for (int cand = BATCH_; cand >= 16; cand >>= 1) {
        const size_t need = FIXED + (size_t)cand * (56 * 5120 + 65536);
        if (need <= ws_size) { BC = cand; break; }
    }
    const int nChunks = BATCH_ / BC;
    const int CT = BC * NPATCH;
    const size_t TD = (size_t)CT * D_;

    bf16* h    = (bf16*)wend;                     // [CT][512] bf16
    bf16* hn   = h + TD;                          // [CT][512] bf16
    bf16* qk   = hn + TD;                         // [CT][1024] bf16
    bf16* ao   = qk + (size_t)CT * 1024;          // [CT][512] bf16
    bf16* vt   = ao + TD;                         // [BC][8][64][64] bf16
    bf16* mid  = qk;                              // [CT][2048] bf16 aliases qk+ao+vt

    // ---- one-time weight packing (f32 [K][N] -> bf16 fragment stream) ----
    packW_k<<<dim3(128, 1, NLAYER), 256, 0, stream>>>(
        Wq, wqkvp, D_, D_, D_, 0,  WELEM, 3 * WELEM);
    packW_k<<<dim3(128, 1, NLAYER), 256, 0, stream>>>(
        Wk, wqkvp, D_, D_, D_, 8,  WELEM, 3 * WELEM);
    packW_k<<<dim3(128, 1, NLAYER), 256, 0, stream>>>(
        Wv, wqkvp, D_, D_, D_, 16, WELEM, 3 * WELEM);
    packW_k<<<dim3(128, 1, NLAYER), 256, 0, stream>>>(
        Wo, wop,   D_, D_, D_, 0,  WELEM, WELEM);
    packW_k<<<dim3(512, 1, NLAYER), 256, 0, stream>>>(
        W1, w1p,   DFF_, D_, D_, 0, WFELEM, WFELEM);
    packW_k<<<dim3(512, 1, NLAYER), 256, 0, stream>>>(
        W2, w2p,   D_, DFF_, DFF_, 0, WFELEM, WFELEM);
    packW_k<<<dim3((D_ * KPAD / 8 + 255) / 256, 1, 1), 256, 0, stream>>>(
        patch_W, pwp, D_, KPAD, 72, 0, 0, 0);
    bqkv_k<<<(NLAYER * 3 * D_ + 255) / 256, 256, 0, stream>>>(bq, bk, bv, bqkv);
    xpad_k<<<((size_t)NTOK_ * KPAD + 255) / 256, 256, 0, stream>>>(x, xpad);

    const int mt  = CT / 128;
    const int g1n = (D_ / 256) * mt;        // N=512 -> 2 col-blocks
    const int gqn = (3 * D_ / 256) * mt;    // N=1536 -> 6
    const int g2n = (DFF_ / 256) * mt;      // N=2048 -> 8

    for (int c = 0; c < nChunks; c++) {
        const size_t tok0 = (size_t)c * CT;

        gemm_bf16_k<false, false, true, false><<<g1n, 512, 0, stream>>>(
            xpad + tok0 * KPAD, pwp, patch_b, nullptr, pos, h, nullptr,
            CT, D_, KPAD, D_ / 256);

        for (int l = 0; l < NLAYER; l++) {
            layernorm_bf16_k<<<CT / 8, 512, 0, stream>>>(h, ln1_g + l * D_, ln1_b + l * D_, hn);
            gemm_bf16_k<false, false, false, true><<<gqn, 512, 0, stream>>>(
                hn, wqkvp + (size_t)l * 3 * WELEM, bqkv + l * 3 * D_, nullptr, nullptr,
                qk, vt, CT, 3 * D_, D_, 3 * D_ / 256);
            attn_mfma_k<<<BC * 2, 256, 0, stream>>>(qk, vt, ao);
            gemm_bf16_k<false, true, false, false><<<g1n, 512, 0, stream>>>(
                ao, wop + (size_t)l * WELEM, bo + l * D_, h, nullptr, h, nullptr,
                CT, D_, D_, D_ / 256);
            layernorm_bf16_k<<<CT / 8, 512, 0, stream>>>(h, ln2_g + l * D_, ln2_b + l * D_, hn);
            gemm_bf16_k<true, false, false, false><<<g2n, 512, 0, stream>>>(
                hn, w1p + (size_t)l * WFELEM, b1 + l * DFF_, nullptr, nullptr,
                mid, nullptr, CT, DFF_, D_, DFF_ / 256);
            gemm_bf16_k<false, true, false, false><<<g1n, 512, 0, stream>>>(
                mid, w2p + (size_t)l * WFELEM, b2 + l * D_, h, nullptr, h, nullptr,
                CT, D_, DFF_, D_ / 256);
        }

        head_k<<<BC, 256, 0, stream>>>(h, fn_g, fn_b, head_W, head_b,
                                       out + (size_t)c * BC * HOR_);
    }
}

// Round 21
// 1945.840 us; speedup vs baseline: 1.0535x; 1.0535x over previous
//
#include <hip/hip_runtime.h>
#include <hip/hip_bf16.h>
#include <math.h>

#define D_      512
#define NPATCH  56
#define DFF_    2048
#define NLAYER  6
#define HEADS   8
#define DH_     64
#define HOR_    24
#define BATCH_  512
#define NTOK_   (BATCH_ * NPATCH)
#define KPAD    96                  // patch K=72 padded to 96 (mult of 32)

typedef __hip_bfloat16 bf16;
typedef __bf16 bf16x8 __attribute__((ext_vector_type(8)));
typedef float  f32x4  __attribute__((ext_vector_type(4)));

__device__ __forceinline__ void gload_lds16(const void* g, void* lds) {
    __builtin_amdgcn_global_load_lds(
        (const __attribute__((address_space(1))) unsigned int*)g,
        (__attribute__((address_space(3))) unsigned int*)lds, 16, 0, 0);
}

// ---------------- block-wide sum over 256 threads ----------------
__device__ __forceinline__ float block_sum256(float v) {
    __shared__ float sm[4];
    const int lane = threadIdx.x & 63;
    const int w    = threadIdx.x >> 6;
    #pragma unroll
    for (int o = 32; o > 0; o >>= 1) v += __shfl_down(v, o);
    __syncthreads();
    if (lane == 0) sm[w] = v;
    __syncthreads();
    return sm[0] + sm[1] + sm[2] + sm[3];
}

// fast tanh-GELU: 0.5x(1+tanh(.79788(x+.044715x^3))) = x - x*rcp(1+exp(2u))
__device__ __forceinline__ float gelu_fast(float xg) {
    const float e = __expf(1.5957691216057308f * (xg + 0.044715f * xg * xg * xg));
    return xg - xg * __builtin_amdgcn_rcpf(1.f + e);
}

// ---------------- transpose + fp32->bf16 with independent layer strides ----------------
__global__ __launch_bounds__(256) void transpose_bf16_k(
    const float* __restrict__ in, bf16* __restrict__ out, int R, int C,
    size_t in_ls, size_t out_ls)
{
    __shared__ float t[32][33];
    in  += (size_t)blockIdx.z * in_ls;
    out += (size_t)blockIdx.z * out_ls;
    const int c0 = blockIdx.x * 32, r0 = blockIdx.y * 32;
    const int x = threadIdx.x & 31, y = threadIdx.x >> 5;
    #pragma unroll
    for (int i = 0; i < 4; i++)
        t[y + i * 8][x] = in[(size_t)(r0 + y + i * 8) * C + c0 + x];
    __syncthreads();
    #pragma unroll
    for (int i = 0; i < 4; i++)
        out[(size_t)(c0 + y + i * 8) * R + r0 + x] = __float2bfloat16(t[x][y + i * 8]);
}

// ---------------- patch_W [72][512] -> bf16 transposed padded [512][96] ----------------
__global__ __launch_bounds__(256) void pwt_k(
    const float* __restrict__ W, bf16* __restrict__ out)
{
    const int idx = blockIdx.x * 256 + threadIdx.x;
    if (idx >= D_ * KPAD) return;
    const int n = idx / KPAD, kk = idx % KPAD;
    out[idx] = (kk < 72) ? __float2bfloat16(W[kk * D_ + n]) : __float2bfloat16(0.f);
}

// ---------------- x [NTOK][72] f32 -> [NTOK][96] bf16 zero-padded ----------------
__global__ __launch_bounds__(256) void xpad_k(
    const float* __restrict__ x, bf16* __restrict__ out)
{
    const size_t idx = (size_t)blockIdx.x * 256 + threadIdx.x;
    if (idx >= (size_t)NTOK_ * KPAD) return;
    const size_t row = idx / KPAD;
    const int kk = (int)(idx - row * KPAD);
    out[idx] = (kk < 72) ? __float2bfloat16(x[row * 72 + kk]) : __float2bfloat16(0.f);
}

// ---------------- concat q/k/v biases -> [NL][1536] f32 ----------------
__global__ __launch_bounds__(256) void bqkv_k(
    const float* __restrict__ bq, const float* __restrict__ bk,
    const float* __restrict__ bv, float* __restrict__ o)
{
    const int idx = blockIdx.x * 256 + threadIdx.x;
    if (idx >= NLAYER * 3 * D_) return;
    const int l = idx / (3 * D_), n = idx % (3 * D_);
    float v;
    if      (n < D_)     v = bq[l * D_ + n];
    else if (n < 2 * D_) v = bk[l * D_ + n - D_];
    else                 v = bv[l * D_ + n - 2 * D_];
    o[idx] = v;
}

// ---------------- LayerNorm: bf16 in -> bf16 out, one wave per row (8 rows/block) ----
__global__ __launch_bounds__(512) void layernorm_bf16_k(
    const bf16* __restrict__ x, const float* __restrict__ g,
    const float* __restrict__ b, bf16* __restrict__ y)
{
    const int w = threadIdx.x >> 6, lane = threadIdx.x & 63;
    const size_t row = (size_t)blockIdx.x * 8 + w;
    const bf16x8 a8 = *(const bf16x8*)((const __bf16*)x + row * D_ + lane * 8);
    float a[8];
    #pragma unroll
    for (int i = 0; i < 8; i++) a[i] = (float)a8[i];
    float s = 0.f;
    #pragma unroll
    for (int i = 0; i < 8; i++) s += a[i];
    #pragma unroll
    for (int o = 32; o > 0; o >>= 1) s += __shfl_xor(s, o);
    const float mean = s * (1.f / 512.f);
    float d[8];
    #pragma unroll
    for (int i = 0; i < 8; i++) d[i] = a[i] - mean;
    float v = 0.f;
    #pragma unroll
    for (int i = 0; i < 8; i++) v += d[i] * d[i];
    #pragma unroll
    for (int o = 32; o > 0; o >>= 1) v += __shfl_xor(v, o);
    const float rstd = rsqrtf(v * (1.f / 512.f) + 1e-5f);
    const float4 g0 = *(const float4*)(g + lane * 8);
    const float4 g1 = *(const float4*)(g + lane * 8 + 4);
    const float4 b0 = *(const float4*)(b + lane * 8);
    const float4 b1 = *(const float4*)(b + lane * 8 + 4);
    const float gg[8] = {g0.x, g0.y, g0.z, g0.w, g1.x, g1.y, g1.z, g1.w};
    const float bb[8] = {b0.x, b0.y, b0.z, b0.w, b1.x, b1.y, b1.z, b1.w};
    bf16x8 o8;
    #pragma unroll
    for (int i = 0; i < 8; i++) o8[i] = (__bf16)(d[i] * rstd * gg[i] + bb[i]);
    *(bf16x8*)((__bf16*)y + row * D_ + lane * 8) = o8;
}

// ---------------- bf16 MFMA GEMM: C[M,N] = A[M,K] @ Bt[N,K]^T -----------------------
// Tile 128M x 256N, 8 waves (2Mx4N), per-wave 64x64 (acc[4][4]). BK=32, 3-buffer
// ring, depth-2 prefetch, counted vmcnt(3), never 0 mid-loop. 16 waves/CU. A+B
// unified in ABs (24 segs); coalesced quad-contiguous staging; 16B chunk
// XOR-permuted within 64B line (same involution on stage source and frag read)
// -> conflict-free ds_read. setprio(1) around the MFMA cluster (T5).
template<bool GELU, bool RESID, bool POS, bool QKVSPLIT>
__global__ __launch_bounds__(512, 4) void gemm_bf16_k(
    const bf16* __restrict__ A, const bf16* __restrict__ Bt,
    const float* __restrict__ bias, const bf16* __restrict__ resid,
    const float* __restrict__ pos, bf16* __restrict__ Cp,
    bf16* __restrict__ vt, int M, int N, int K, int nx)
{
    __shared__ __align__(16) bf16 ABs[3][384 * 32];  // seg 0-7: A rows, 8-23: B rows; 72 KB
    const int tid  = threadIdx.x;
    const int wid  = tid >> 6;        // 0..7
    const int lane = tid & 63;

    // bijective XCD swizzle (m204)
    const int nwg = gridDim.x;
    const int q8 = nwg >> 3, r8 = nwg & 7;
    const int xcd = blockIdx.x & 7, idx8 = blockIdx.x >> 3;
    const int swz = (xcd < r8 ? xcd * (q8 + 1) : r8 * (q8 + 1) + (xcd - r8) * q8) + idx8;
    const int n0 = (swz % nx) * 256;
    const int m0 = (swz / nx) * 128;
    const int wr = wid >> 2, wc = wid & 3;   // 2 row-bands x 4 col-bands of 64

    f32x4 acc[4][4];
    #pragma unroll
    for (int m = 0; m < 4; m++)
        #pragma unroll
        for (int n = 0; n < 4; n++) acc[m][n] = f32x4{0.f, 0.f, 0.f, 0.f};

    // staging: lane l -> row l>>2 (quad covers one 64B line), chunk XOR-permuted in line.
    // Wave wid stages segments 3*wid .. 3*wid+2 of [A(0-7) | B(8-23)].
    const int srow = lane >> 2;
    const int schunk = ((lane & 3) ^ ((lane >> 3) & 3)) * 8;
    const bf16* sp[3];
    int soff[3];
    #pragma unroll
    for (int i = 0; i < 3; i++) {
        const int s = wid * 3 + i;
        soff[i] = s * 512;
        sp[i] = (s < 8)
            ? A  + (size_t)(m0 + s * 16 + srow) * K + schunk
            : Bt + (size_t)(n0 + (s - 8) * 16 + srow) * K + schunk;
    }

    // frag read: row fr, k-chunk qg stored at slot qg ^ ((fr>>1)&3)
    const int fr = lane & 15;
    const int qg = lane >> 4;
    const int roff = fr * 32 + ((qg ^ ((fr >> 1) & 3)) * 8);

    const int nt = K >> 5;
    #define STAGE(buf, kt)  do {                                   \
        gload_lds16(sp[0] + ((kt) << 5), &ABs[buf][soff[0]]);      \
        gload_lds16(sp[1] + ((kt) << 5), &ABs[buf][soff[1]]);      \
        gload_lds16(sp[2] + ((kt) << 5), &ABs[buf][soff[2]]); } while (0)

    // prologue: stage K-steps 0 and 1
    STAGE(0, 0);
    STAGE(1, 1);

    int cur = 0, nxt = 2;
    for (int t = 0; t < nt; t++) {
        if (t < nt - 1) asm volatile("s_waitcnt vmcnt(3)" ::: "memory");
        else            asm volatile("s_waitcnt vmcnt(0)" ::: "memory");
        __builtin_amdgcn_s_barrier();
        __builtin_amdgcn_sched_barrier(0);
        bf16x8 af[4], bg[4];
        #pragma unroll
        for (int m = 0; m < 4; m++)
            af[m] = *(const bf16x8*)&ABs[cur][(wr * 4 + m) * 512 + roff];
        #pragma unroll
        for (int n = 0; n < 4; n++)
            bg[n] = *(const bf16x8*)&ABs[cur][(8 + wc * 4 + n) * 512 + roff];
        if (t + 2 < nt) STAGE(nxt, t + 2);
        __builtin_amdgcn_s_setprio(1);
        #pragma unroll
        for (int m = 0; m < 4; m++)
            #pragma unroll
            for (int n = 0; n < 4; n++)
                acc[m][n] = __builtin_amdgcn_mfma_f32_16x16x32_bf16(af[m], bg[n], acc[m][n], 0, 0, 0);
        __builtin_amdgcn_s_setprio(0);
        cur = (cur == 2) ? 0 : cur + 1;
        nxt = (nxt == 2) ? 0 : nxt + 1;
    }
    #undef STAGE

    const int rq = qg * 4;
    #pragma unroll
    for (int m = 0; m < 4; m++) {
        #pragma unroll
        for (int n = 0; n < 4; n++) {
            const int col = n0 + wc * 64 + n * 16 + fr;
            const float bcol = bias[col];
            #pragma unroll
            for (int j = 0; j < 4; j++) {
                const int row = m0 + wr * 64 + m * 16 + rq + j;
                float c = acc[m][n][j] + bcol;
                if (GELU)  c = gelu_fast(c);
                if (RESID) c += __bfloat162float(resid[(size_t)row * N + col]);
                if (POS)   c += pos[(size_t)(row % NPATCH) * D_ + col];
                if (QKVSPLIT) {
                    if (col < 1024) {
                        Cp[(size_t)row * 1024 + col] = __float2bfloat16(c);
                    } else {
                        const int c2 = col - 1024, hh = c2 >> 6, dd = c2 & 63;
                        const int bb = row / NPATCH, pp = row - bb * NPATCH;
                        vt[(((size_t)bb * 8 + hh) * 64 + dd) * 64 + pp] = __float2bfloat16(c);
                    }
                } else {
                    Cp[(size_t)row * N + col] = __float2bfloat16(c);
                }
            }
        }
    }
}

// ---------------- MFMA attention: 1 wave per (b,h); no cross-wave sync ----------------
__global__ __launch_bounds__(256) void attn_mfma_k(
    const bf16* __restrict__ qk, const bf16* __restrict__ vt,
    bf16* __restrict__ ao)
{
    __shared__ __align__(16) bf16 St[4][64 * 72];
    const int tid  = threadIdx.x;
    const int w    = tid >> 6, lane = tid & 63;
    const int bh   = blockIdx.x * 4 + w;
    const int b    = bh >> 3, hh = bh & 7;
    const int fr   = lane & 15;
    const int qg   = lane >> 4;
    const int kc   = qg * 8;

    const bf16* Qb = qk + (size_t)b * NPATCH * 1024 + hh * 64;
    const bf16* Kb = Qb + 512;
    const bf16* Vb = vt + (size_t)bh * 4096;

    bf16x8 qf[4][2], kf[4][2];
    #pragma unroll
    for (int m = 0; m < 4; m++)
        #pragma unroll
        for (int ks = 0; ks < 2; ks++) {
            qf[m][ks] = *(const bf16x8*)&Qb[(size_t)(m * 16 + fr) * 1024 + ks * 32 + kc];
            kf[m][ks] = *(const bf16x8*)&Kb[(size_t)(m * 16 + fr) * 1024 + ks * 32 + kc];
        }

    f32x4 acc[4][4];
    #pragma unroll
    for (int m = 0; m < 4; m++)
        #pragma unroll
        for (int n = 0; n < 4; n++) acc[m][n] = f32x4{0.f, 0.f, 0.f, 0.f};
    __builtin_amdgcn_s_setprio(1);
    #pragma unroll
    for (int ks = 0; ks < 2; ks++)
        #pragma unroll
        for (int m = 0; m < 4; m++)
            #pragma unroll
            for (int n = 0; n < 4; n++)
                acc[m][n] = __builtin_amdgcn_mfma_f32_16x16x32_bf16(qf[m][ks], kf[n][ks], acc[m][n], 0, 0, 0);
    __builtin_amdgcn_s_setprio(0);

    bf16x8 vf[4][2];
    #pragma unroll
    for (int n = 0; n < 4; n++)
        #pragma unroll
        for (int ks = 0; ks < 2; ks++)
            vf[n][ks] = *(const bf16x8*)&Vb[(size_t)(n * 16 + fr) * 64 + ks * 32 + kc];

    const float slope = exp2f(-(float)(hh + 1));
    bf16* Sw = St[w];
    #pragma unroll
    for (int m = 0; m < 4; m++) {
        #pragma unroll
        for (int j = 0; j < 4; j++) {
            const int r = m * 16 + qg * 4 + j;
            float s[4];
            #pragma unroll
            for (int n = 0; n < 4; n++) {
                const int col = n * 16 + fr;
                float sv = acc[m][n][j] * 0.125f - slope * fabsf((float)(r - col));
                s[n] = (col >= NPATCH) ? -1e30f : sv;
            }
            float mx = fmaxf(fmaxf(s[0], s[1]), fmaxf(s[2], s[3]));
            mx = fmaxf(mx, __shfl_xor(mx, 1));
            mx = fmaxf(mx, __shfl_xor(mx, 2));
            mx = fmaxf(mx, __shfl_xor(mx, 4));
            mx = fmaxf(mx, __shfl_xor(mx, 8));
            float p[4], sum = 0.f;
            #pragma unroll
            for (int n = 0; n < 4; n++) { p[n] = __expf(s[n] - mx); sum += p[n]; }
            sum += __shfl_xor(sum, 1);
            sum += __shfl_xor(sum, 2);
            sum += __shfl_xor(sum, 4);
            sum += __shfl_xor(sum, 8);
            const float inv = 1.f / sum;
            #pragma unroll
            for (int n = 0; n < 4; n++)
                Sw[r * 72 + n * 16 + fr] = __float2bfloat16(p[n] * inv);
        }
    }

    #pragma unroll
    for (int m = 0; m < 4; m++)
        #pragma unroll
        for (int n = 0; n < 4; n++) acc[m][n] = f32x4{0.f, 0.f, 0.f, 0.f};
    __builtin_amdgcn_s_setprio(1);
    #pragma unroll
    for (int m = 0; m < 4; m++)
        #pragma unroll
        for (int ks = 0; ks < 2; ks++) {
            const bf16x8 pf = *(const bf16x8*)&Sw[(m * 16 + fr) * 72 + ks * 32 + kc];
            #pragma unroll
            for (int n = 0; n < 4; n++)
                acc[m][n] = __builtin_amdgcn_mfma_f32_16x16x32_bf16(pf, vf[n][ks], acc[m][n], 0, 0, 0);
        }
    __builtin_amdgcn_s_setprio(0);

    bf16* Ob = ao + (size_t)b * NPATCH * 512 + hh * 64;
    #pragma unroll
    for (int m = 0; m < 4; m++)
        #pragma unroll
        for (int j = 0; j < 4; j++) {
            const int r = m * 16 + qg * 4 + j;
            if (r < NPATCH)
                #pragma unroll
                for (int n = 0; n < 4; n++)
                    Ob[(size_t)r * 512 + n * 16 + fr] = __float2bfloat16(acc[m][n][j]);
        }
}

// ---------------- fused mean pool + final LN + head (bf16 h): one block per row ------
__global__ __launch_bounds__(256) void head_k(
    const bf16* __restrict__ h, const float* __restrict__ g,
    const float* __restrict__ bb, const float* __restrict__ hW,
    const float* __restrict__ hb, float* __restrict__ out)
{
    const int b = blockIdx.x;
    __shared__ float row[D_];
    const int tid = threadIdx.x;
    float v0 = 0.f, v1 = 0.f;
    #pragma unroll
    for (int p = 0; p < NPATCH; p++) {
        const bf16* hr = h + (size_t)b * NPATCH * D_ + (size_t)p * D_;
        v0 += __bfloat162float(hr[tid]);
        v1 += __bfloat162float(hr[tid + 256]);
    }
    v0 *= (1.f / (float)NPATCH);
    v1 *= (1.f / (float)NPATCH);
    const float mean = block_sum256(v0 + v1) * (1.f / 512.f);
    const float d0 = v0 - mean, d1 = v1 - mean;
    const float var = block_sum256(d0 * d0 + d1 * d1) * (1.f / 512.f);
    const float rstd = rsqrtf(var + 1e-5f);
    row[tid]       = d0 * rstd * g[tid]       + bb[tid];
    row[tid + 256] = d1 * rstd * g[tid + 256] + bb[tid + 256];
    __syncthreads();
    if (tid < HOR_) {
        float acc = hb[tid];
        for (int kk = 0; kk < D_; kk++) acc = fmaf(row[kk], hW[kk * HOR_ + tid], acc);
        out[(size_t)b * HOR_ + tid] = acc;
    }
}

extern "C" void kernel_launch(void* const* d_in, const int* in_sizes, int n_in,
                              void* d_out, int out_size, void* d_ws, size_t ws_size,
                              hipStream_t stream)
{
    const float* x       = (const float*)d_in[0];
    const float* patch_W = (const float*)d_in[1];
    const float* patch_b = (const float*)d_in[2];
    const float* pos     = (const float*)d_in[3];
    const float* ln1_g   = (const float*)d_in[4];
    const float* ln1_b   = (const float*)d_in[5];
    const float* Wq      = (const float*)d_in[6];
    const float* bq      = (const float*)d_in[7];
    const float* Wk      = (const float*)d_in[8];
    const float* bk      = (const float*)d_in[9];
    const float* Wv      = (const float*)d_in[10];
    const float* bv      = (const float*)d_in[11];
    const float* Wo      = (const float*)d_in[12];
    const float* bo      = (const float*)d_in[13];
    const float* ln2_g   = (const float*)d_in[14];
    const float* ln2_b   = (const float*)d_in[15];
    const float* W1      = (const float*)d_in[16];
    const float* b1      = (const float*)d_in[17];
    const float* W2      = (const float*)d_in[18];
    const float* b2      = (const float*)d_in[19];
    const float* fn_g    = (const float*)d_in[20];
    const float* fn_b    = (const float*)d_in[21];
    const float* head_W  = (const float*)d_in[22];
    const float* head_b  = (const float*)d_in[23];
    float* out = (float*)d_out;

    // ---- workspace: converted weights (per-call), then activations ----
    const size_t WELEM  = (size_t)D_ * D_;
    const size_t WFELEM = (size_t)D_ * DFF_;
    bf16* wqkvt = (bf16*)d_ws;                       // [6][1536][512]
    bf16* wot   = wqkvt + (size_t)NLAYER * 3 * WELEM;
    bf16* w1t   = wot   + (size_t)NLAYER * WELEM;    // [6][2048][512]
    bf16* w2t   = w1t   + (size_t)NLAYER * WFELEM;   // [6][512][2048]
    bf16* pwt   = w2t   + (size_t)NLAYER * WFELEM;   // [512][96]
    float* bqkv = (float*)(pwt + (size_t)D_ * KPAD); // [6][1536]
    bf16* xpad  = (bf16*)(bqkv + NLAYER * 3 * D_);   // [NTOK][96]
    char* wend  = (char*)(xpad + (size_t)NTOK_ * KPAD);
    const size_t FIXED = (size_t)(wend - (char*)d_ws);

    // per-token activation bytes: h 1024 + hn 1024 + qk 2048 + ao 1024 (all bf16)
    int BC = 16;
    for (int cand = BATCH_; cand >= 16; cand >>= 1) {
        const size_t need = FIXED + (size_t)cand * (56 * 5120 + 65536);
        if (need <= ws_size) { BC = cand; break; }
    }
    const int nChunks = BATCH_ / BC;
    const int CT = BC * NPATCH;
    const size_t TD = (size_t)CT * D_;

    bf16* h    = (bf16*)wend;                     // [CT][512] bf16
    bf16* hn   = h + TD;                          // [CT][512] bf16
    bf16* qk   = hn + TD;                         // [CT][1024] bf16
    bf16* ao   = qk + (size_t)CT * 1024;          // [CT][512] bf16
    bf16* vt   = ao + TD;                         // [BC][8][64][64] bf16
    bf16* mid  = qk;                              // [CT][2048] bf16 aliases qk+ao+vt

    // ---- one-time conversions ----
    transpose_bf16_k<<<dim3(16, 16, NLAYER), 256, 0, stream>>>(
        Wq, wqkvt,                 D_, D_, WELEM, 3 * WELEM);
    transpose_bf16_k<<<dim3(16, 16, NLAYER), 256, 0, stream>>>(
        Wk, wqkvt + WELEM,         D_, D_, WELEM, 3 * WELEM);
    transpose_bf16_k<<<dim3(16, 16, NLAYER), 256, 0, stream>>>(
        Wv, wqkvt + 2 * WELEM,     D_, D_, WELEM, 3 * WELEM);
    transpose_bf16_k<<<dim3(16, 16, NLAYER), 256, 0, stream>>>(
        Wo, wot,                   D_, D_, WELEM, WELEM);
    transpose_bf16_k<<<dim3(64, 16, NLAYER), 256, 0, stream>>>(
        W1, w1t,                   D_, DFF_, WFELEM, WFELEM);
    transpose_bf16_k<<<dim3(16, 64, NLAYER), 256, 0, stream>>>(
        W2, w2t,                   DFF_, D_, WFELEM, WFELEM);
    pwt_k<<<(D_ * KPAD + 255) / 256, 256, 0, stream>>>(patch_W, pwt);
    bqkv_k<<<(NLAYER * 3 * D_ + 255) / 256, 256, 0, stream>>>(bq, bk, bv, bqkv);
    xpad_k<<<((size_t)NTOK_ * KPAD + 255) / 256, 256, 0, stream>>>(x, xpad);

    const int mt  = CT / 128;
    const int g1n = (D_ / 256) * mt;        // N=512 -> 2 col-blocks
    const int gqn = (3 * D_ / 256) * mt;    // N=1536 -> 6
    const int g2n = (DFF_ / 256) * mt;      // N=2048 -> 8

    for (int c = 0; c < nChunks; c++) {
        const size_t tok0 = (size_t)c * CT;

        gemm_bf16_k<false, false, true, false><<<g1n, 512, 0, stream>>>(
            xpad + tok0 * KPAD, pwt, patch_b, nullptr, pos, h, nullptr,
            CT, D_, KPAD, D_ / 256);

        for (int l = 0; l < NLAYER; l++) {
            layernorm_bf16_k<<<CT / 8, 512, 0, stream>>>(h, ln1_g + l * D_, ln1_b + l * D_, hn);
            gemm_bf16_k<false, false, false, true><<<gqn, 512, 0, stream>>>(
                hn, wqkvt + (size_t)l * 3 * WELEM, bqkv + l * 3 * D_, nullptr, nullptr,
                qk, vt, CT, 3 * D_, D_, 3 * D_ / 256);
            attn_mfma_k<<<BC * 2, 256, 0, stream>>>(qk, vt, ao);
            gemm_bf16_k<false, true, false, false><<<g1n, 512, 0, stream>>>(
                ao, wot + (size_t)l * WELEM, bo + l * D_, h, nullptr, h, nullptr,
                CT, D_, D_, D_ / 256);
            layernorm_bf16_k<<<CT / 8, 512, 0, stream>>>(h, ln2_g + l * D_, ln2_b + l * D_, hn);
            gemm_bf16_k<true, false, false, false><<<g2n, 512, 0, stream>>>(
                hn, w1t + (size_t)l * WFELEM, b1 + l * DFF_, nullptr, nullptr,
                mid, nullptr, CT, DFF_, D_, DFF_ / 256);
            gemm_bf16_k<false, true, false, false><<<g1n, 512, 0, stream>>>(
                mid, w2t + (size_t)l * WFELEM, b2 + l * D_, h, nullptr, h, nullptr,
                CT, D_, DFF_, D_ / 256);
        }

        head_k<<<BC, 256, 0, stream>>>(h, fn_g, fn_b, head_W, head_b,
                                       out + (size_t)c * BC * HOR_);
    }
}